// Round 6
// baseline (76.630 us; speedup 1.0000x reference)
//
#include <hip/hip_runtime.h>
#include <hip/hip_bf16.h>
#include <math.h>

#define EMB 30
#define NS 16  // D-split blocks per q-tile; each block's 4 waves are 4 sub-splits

typedef __attribute__((ext_vector_type(8))) short bf16x8;
typedef __attribute__((ext_vector_type(4))) float f32x4;
typedef __attribute__((ext_vector_type(2))) _Float16 f16x2;

__device__ __forceinline__ float leakyf(float x) { return x > 0.0f ? x : 0.1f * x; }

__device__ __forceinline__ unsigned short f2b(float x) {
  __hip_bfloat16 h = __float2bfloat16(x);
  union { __hip_bfloat16 h; unsigned short u; } cv;
  cv.h = h;
  return cv.u;
}

// true packed f16 min/max (bit-pattern in unsigned) — forces v_pk_*_f16
__device__ __forceinline__ unsigned pkmax(unsigned a, unsigned b) {
  unsigned d;
  asm("v_pk_max_f16 %0, %1, %2" : "=v"(d) : "v"(a), "v"(b));
  return d;
}
__device__ __forceinline__ unsigned pkmin(unsigned a, unsigned b) {
  unsigned d;
  asm("v_pk_min_f16 %0, %1, %2" : "=v"(d) : "v"(a), "v"(b));
  return d;
}
__device__ __forceinline__ unsigned cvtpku(float a, float b) {
  return __builtin_bit_cast(unsigned, __builtin_amdgcn_cvt_pkrtz(a, b));
}

// packed insert into descending-sorted t[5]
__device__ __forceinline__ void ins5h(unsigned (&t)[5], unsigned v) {
  t[4] = pkmax(t[4], v);
  unsigned a;
  a = pkmax(t[3], t[4]); t[4] = pkmin(t[3], t[4]); t[3] = a;
  a = pkmax(t[2], t[3]); t[3] = pkmin(t[2], t[3]); t[2] = a;
  a = pkmax(t[1], t[2]); t[2] = pkmin(t[1], t[2]); t[1] = a;
  a = pkmax(t[0], t[1]); t[1] = pkmin(t[0], t[1]); t[0] = a;
}

// packed top-5 of merge(a,b), both sorted descending
__device__ __forceinline__ void merge5h(unsigned (&a)[5], const unsigned (&b)[5]) {
  unsigned c0 = pkmax(a[0], b[0]);
  unsigned c1 = pkmax(pkmax(pkmin(a[0], b[0]), a[1]), b[1]);
  unsigned c2 = pkmax(pkmax(pkmin(a[0], b[1]), pkmin(a[1], b[0])), pkmax(a[2], b[2]));
  unsigned c3 = pkmax(pkmax(pkmin(a[0], b[2]), pkmin(a[1], b[1])),
                      pkmax(pkmin(a[2], b[0]), pkmax(a[3], b[3])));
  unsigned c4 = pkmax(pkmax(pkmax(pkmin(a[0], b[3]), pkmin(a[1], b[2])),
                            pkmax(pkmin(a[2], b[1]), pkmin(a[3], b[0]))),
                      pkmax(a[4], b[4]));
  a[0] = c0; a[1] = c1; a[2] = c2; a[3] = c3; a[4] = c4;
}

// float top-5 merge (pool stage)
__device__ __forceinline__ void merge5(float (&a)[5], const float (&b)[5]) {
  float c0 = fmaxf(a[0], b[0]);
  float c1 = fmaxf(fmaxf(fminf(a[0], b[0]), a[1]), b[1]);
  float c2 = fmaxf(fmaxf(fminf(a[0], b[1]), fminf(a[1], b[0])), fmaxf(a[2], b[2]));
  float c3 = fmaxf(fmaxf(fminf(a[0], b[2]), fminf(a[1], b[1])),
                   fmaxf(fminf(a[2], b[0]), fmaxf(a[3], b[3])));
  float c4 = fmaxf(fmaxf(fmaxf(fminf(a[0], b[3]), fminf(a[1], b[2])),
                         fmaxf(fminf(a[2], b[1]), fminf(a[3], b[0]))),
                   fmaxf(a[4], b[4]));
  a[0] = c0; a[1] = c1; a[2] = c2; a[3] = c3; a[4] = c4;
}

// butterfly merge round over j-lanes via single-instruction ds_swizzle
template <int PAT>
__device__ __forceinline__ void bfly_round(unsigned (&t)[8][5]) {
#pragma unroll
  for (int li = 0; li < 8; ++li) {
    unsigned b[5];
#pragma unroll
    for (int k = 0; k < 5; ++k)
      b[k] = (unsigned)__builtin_amdgcn_ds_swizzle((int)t[li][k], PAT);
    merge5h(t[li], b);
  }
}

// Fused prep: questions -> qr/qc [L][32] bf16 + logits; docs -> interleaved
// cmb[j][4][32] bf16 (slots: 0=d1 raw, 1=d1 conv, 2=d2 raw, 3=d2 conv).
__global__ __launch_bounds__(256) void prep_all_kernel(
    const float* __restrict__ Xq, const float* __restrict__ X1,
    const float* __restrict__ X2, int Q, int D,
    const float* __restrict__ Wc, const float* __restrict__ bc,
    const float* __restrict__ qidf, const float* __restrict__ Wqw,
    unsigned short* __restrict__ qr, unsigned short* __restrict__ qc,
    unsigned short* __restrict__ cmb, float* __restrict__ logits) {
  __shared__ float sX[258 * EMB];
  int tid = threadIdx.x;
  int nbQ = Q >> 8, nbD = D >> 8;
  int b = blockIdx.x;
  const float* X;
  int L, l0, slot = 0;
  bool isQ = false;
  if (b < nbQ) { X = Xq; L = Q; l0 = b << 8; isQ = true; }
  else if (b < nbQ + nbD) { X = X1; L = D; l0 = (b - nbQ) << 8; slot = 0; }
  else { X = X2; L = D; l0 = (b - nbQ - nbD) << 8; slot = 2; }

  int base = l0 * EMB - EMB;
  int lim = L * EMB;
  for (int idx = tid; idx < 258 * EMB; idx += 256) {
    int g = base + idx;
    sX[idx] = (g >= 0 && g < lim) ? X[g] : 0.0f;
  }
  __syncthreads();

  int l = l0 + tid;                    // L is a multiple of 256
  float xm[EMB], x0[EMB], xp[EMB], y[EMB];
#pragma unroll
  for (int i = 0; i < EMB; ++i) xm[i] = sX[tid * EMB + i];
#pragma unroll
  for (int i = 0; i < EMB; ++i) x0[i] = sX[(tid + 1) * EMB + i];
#pragma unroll
  for (int i = 0; i < EMB; ++i) xp[i] = sX[(tid + 2) * EMB + i];

  float sr = 0.0f, sc = 0.0f, lg = 0.0f;
#pragma unroll
  for (int i = 0; i < EMB; ++i) sr += x0[i] * x0[i];
#pragma unroll 1
  for (int o = 0; o < EMB; ++o) {
    float acc = bc[o];                 // uniform -> scalar loads
#pragma unroll
    for (int i = 0; i < EMB; ++i) {
      acc += Wc[o * 90 + i * 3 + 0] * xm[i];
      acc += Wc[o * 90 + i * 3 + 1] * x0[i];
      acc += Wc[o * 90 + i * 3 + 2] * xp[i];
    }
    float v = leakyf(acc) + x0[o];
    y[o] = v;
    sc += v * v;
    lg += v * Wqw[o];
  }
  float rnr = 1.0f / sqrtf(sr);
  float rnc = 1.0f / sqrtf(sc);
  if (isQ) logits[l] = lg + qidf[l] * Wqw[EMB];

  unsigned int rp[16], cp[16];
#pragma unroll
  for (int k = 0; k < 15; ++k) {
    rp[k] = (unsigned int)f2b(x0[2 * k] * rnr) | ((unsigned int)f2b(x0[2 * k + 1] * rnr) << 16);
    cp[k] = (unsigned int)f2b(y[2 * k] * rnc) | ((unsigned int)f2b(y[2 * k + 1] * rnc) << 16);
  }
  rp[15] = 0u; cp[15] = 0u;
  unsigned int *rw, *cw;
  if (isQ) {
    rw = (unsigned int*)(qr + (size_t)l * 32);
    cw = (unsigned int*)(qc + (size_t)l * 32);
  } else {
    rw = (unsigned int*)(cmb + (size_t)l * 128 + slot * 32);
    cw = rw + 16;
  }
#pragma unroll
  for (int k = 0; k < 16; ++k) { rw[k] = rp[k]; cw[k] = cp[k]; }
}

// MFMA sims + packed-f16 top-5 + ds_swizzle butterfly + cross-wave LDS merge.
// blockIdx = qt*NS + ds; wave w = sub-split ds*4+w (chunk=D/(NS*4)=128 j's).
// Explicit 2-deep load pipeline (named regs) to raise MLP; launch_bounds(,5)
// caps VGPR ~102 so 5 waves/SIMD stay resident.
__global__ __launch_bounds__(256, 5) void main_kernel(
    const unsigned short* __restrict__ qrA, const unsigned short* __restrict__ qcA,
    const unsigned short* __restrict__ cmb,
    float* __restrict__ partials, int Q, int D) {
  __shared__ unsigned sm[4][16][10];
  int tid = threadIdx.x;
  int wave = tid >> 6, lane = tid & 63;
  int lo = lane & 15, hi = lane >> 4;
  int qt = blockIdx.x >> 4, ds = blockIdx.x & (NS - 1);
  int qrow = qt * 16 + lo;
  bf16x8 aR = *(const bf16x8*)(qrA + (size_t)qrow * 32 + hi * 8);
  bf16x8 aC = *(const bf16x8*)(qcA + (size_t)qrow * 32 + hi * 8);
  int chunk = D / (NS * 4);            // 128 j's per wave
  int j0 = (ds * 4 + wave) * chunk;
  unsigned t[8][5];                    // lists: [r*2+0]=raw(d1,d2) [r*2+1]=conv
#pragma unroll
  for (int li = 0; li < 8; ++li)
#pragma unroll
    for (int k = 0; k < 5; ++k) t[li][k] = 0xC000C000u;  // packed f16 -2.0

  const unsigned short* pj = cmb + (size_t)(j0 + lo) * 128 + hi * 8;

#define LD4(P, X0, X1, X2, X3)                                                 \
  X0 = *(const bf16x8*)(P);        X1 = *(const bf16x8*)((P) + 32);            \
  X2 = *(const bf16x8*)((P) + 64); X3 = *(const bf16x8*)((P) + 96);

#define PROC4(X0, X1, X2, X3)                                                  \
  {                                                                            \
    f32x4 z = {0.0f, 0.0f, 0.0f, 0.0f};                                        \
    f32x4 s0 = __builtin_amdgcn_mfma_f32_16x16x32_bf16(aR, X0, z, 0, 0, 0);    \
    f32x4 s1 = __builtin_amdgcn_mfma_f32_16x16x32_bf16(aC, X1, z, 0, 0, 0);    \
    f32x4 s2 = __builtin_amdgcn_mfma_f32_16x16x32_bf16(aR, X2, z, 0, 0, 0);    \
    f32x4 s3 = __builtin_amdgcn_mfma_f32_16x16x32_bf16(aC, X3, z, 0, 0, 0);    \
    _Pragma("unroll")                                                          \
    for (int r = 0; r < 4; ++r) {                                              \
      ins5h(t[r * 2 + 0], cvtpku(s0[r], s2[r]));                               \
      ins5h(t[r * 2 + 1], cvtpku(s1[r], s3[r]));                               \
    }                                                                          \
  }

  bf16x8 A0, A1, A2, A3, C0, C1, C2, C3;
  LD4(pj, A0, A1, A2, A3);
#pragma unroll
  for (int p = 0; p < 4; ++p) {        // 4 trips x 2 iterations = chunk/16
    LD4(pj + 2048, C0, C1, C2, C3);    // prefetch odd batch
    PROC4(A0, A1, A2, A3);
    LD4(pj + 4096, A0, A1, A2, A3);    // prefetch next even (dead on last trip -> DCE'd)
    PROC4(C0, C1, C2, C3);
    pj += 4096;
  }
#undef LD4
#undef PROC4

  // butterfly over the 16 j-lanes (xor 1,2,4,8), single-instr ds_swizzle
  bfly_round<0x041F>(t);
  bfly_round<0x081F>(t);
  bfly_round<0x101F>(t);
  bfly_round<0x201F>(t);

  if (lo == 0) {
#pragma unroll
    for (int r = 0; r < 4; ++r) {
      int qm = hi * 4 + r;
#pragma unroll
      for (int li = 0; li < 2; ++li)
#pragma unroll
        for (int k = 0; k < 5; ++k) sm[wave][qm][li * 5 + k] = t[r * 2 + li][k];
    }
  }
  __syncthreads();
  if (tid < 16) {
    unsigned T[2][5];
#pragma unroll
    for (int li = 0; li < 2; ++li)
#pragma unroll
      for (int k = 0; k < 5; ++k) T[li][k] = sm[0][tid][li * 5 + k];
#pragma unroll
    for (int w = 1; w < 4; ++w) {
#pragma unroll
      for (int li = 0; li < 2; ++li) {
        unsigned b[5];
#pragma unroll
        for (int k = 0; k < 5; ++k) b[k] = sm[w][tid][li * 5 + k];
        merge5h(T[li], b);
      }
    }
    // unpack: [0..4]=d1 raw, [5..9]=d1 conv, [10..14]=d2 raw, [15..19]=d2 conv
    float* dst = partials + ((size_t)(qt * 16 + tid) * NS + ds) * 20;
#pragma unroll
    for (int k = 0; k < 5; ++k) {
      f16x2 t0 = __builtin_bit_cast(f16x2, T[0][k]);
      f16x2 t1 = __builtin_bit_cast(f16x2, T[1][k]);
      dst[k]      = (float)t0[0];
      dst[5 + k]  = (float)t1[0];
      dst[10 + k] = (float)t0[1];
      dst[15 + k] = (float)t1[1];
    }
  }
}

// Parallel pool: block = 16 q's x 16 splits. Redundant block softmax (M,S),
// LDS-staged coalesced partial loads, shfl-tree split merge, MLP, block sums.
__global__ __launch_bounds__(256) void pool_kernel(
    const float* __restrict__ logits, const float* __restrict__ partials,
    const float* __restrict__ W1, const float* __restrict__ W2,
    float* __restrict__ blockSums, int Q) {
  __shared__ float sred[4];
  __shared__ float sP[16 * 321];
  int tid = threadIdx.x;
  int lane = tid & 63, wave = tid >> 6;

  // redundant softmax stats over all logits (L2-resident, coalesced)
  float lmax = -3.0e38f;
  for (int q = tid; q < Q; q += 256) lmax = fmaxf(lmax, logits[q]);
#pragma unroll
  for (int m = 1; m < 64; m <<= 1) lmax = fmaxf(lmax, __shfl_xor(lmax, m));
  if (lane == 0) sred[wave] = lmax;
  __syncthreads();
  float M = fmaxf(fmaxf(sred[0], sred[1]), fmaxf(sred[2], sred[3]));
  __syncthreads();
  float lsum = 0.0f;
  for (int q = tid; q < Q; q += 256) lsum += expf(logits[q] - M);
#pragma unroll
  for (int m = 1; m < 64; m <<= 1) lsum += __shfl_xor(lsum, m);
  if (lane == 0) sred[wave] = lsum;
  __syncthreads();
  float rS = 1.0f / (sred[0] + sred[1] + sred[2] + sred[3]);

  // stage this block's 16 q's of partials: fully coalesced global -> LDS
  size_t base = (size_t)blockIdx.x * 16 * NS * 20;
  for (int k = tid; k < 16 * NS * 20; k += 256) {
    int ql = k / 320, r = k - ql * 320;
    sP[ql * 321 + r] = partials[base + k];
  }
  __syncthreads();

  int ql = tid >> 4, dsp = tid & 15;
  int qglob = blockIdx.x * 16 + ql;
  float T[4][5];
#pragma unroll
  for (int li = 0; li < 4; ++li)
#pragma unroll
    for (int k = 0; k < 5; ++k) T[li][k] = sP[ql * 321 + dsp * 20 + li * 5 + k];
  // merge across the 16 splits: xor tree within 16-lane groups
#pragma unroll
  for (int m = 8; m >= 1; m >>= 1) {
#pragma unroll
    for (int li = 0; li < 4; ++li) {
      float b[5];
#pragma unroll
      for (int k = 0; k < 5; ++k) b[k] = __shfl_xor(T[li][k], m);
      merge5(T[li], b);
    }
  }
  // all 16 lanes of a q-group now hold the full merge; lane dsp==0 emits
  float s1 = 0.0f, s2 = 0.0f;
  if (dsp == 0) {
    float w = expf(logits[qglob] - M) * rS;
#pragma unroll
    for (int d = 0; d < 2; ++d) {
      const float (&Ti)[5] = T[d ? 2 : 0];   // raw
      const float (&Ts)[5] = T[d ? 3 : 1];   // conv
      float c = 0.0f;
#pragma unroll
      for (int k = 0; k < 5; ++k) c += (Ti[k] > 0.999f) ? 1.0f : 0.0f;  // min(cnt,5)
      float tmp[6];
      tmp[0] = (Ti[0] > 0.999f) ? 1.0f : 0.0f;
      tmp[1] = c * 0.2f;
      tmp[2] = Ti[0];
      tmp[3] = (Ti[0] + Ti[1] + Ti[2] + Ti[3] + Ti[4]) * 0.2f;
      tmp[4] = Ts[0];
      tmp[5] = (Ts[0] + Ts[1] + Ts[2] + Ts[3] + Ts[4]) * 0.2f;
      float lov = 0.0f;
#pragma unroll
      for (int r = 0; r < 8; ++r) {
        float h = 0.0f;
#pragma unroll
        for (int cidx = 0; cidx < 6; ++cidx) h += W1[r * 6 + cidx] * tmp[cidx];
        lov += W2[r] * leakyf(h);
      }
      if (d == 0) s1 = lov * w; else s2 = lov * w;
    }
  }
  // block reduce
  __shared__ float r1[4], r2[4];
#pragma unroll
  for (int m = 1; m < 64; m <<= 1) { s1 += __shfl_xor(s1, m); s2 += __shfl_xor(s2, m); }
  if (lane == 0) { r1[wave] = s1; r2[wave] = s2; }
  __syncthreads();
  if (tid == 0) {
    blockSums[blockIdx.x * 2]     = r1[0] + r1[1] + r1[2] + r1[3];
    blockSums[blockIdx.x * 2 + 1] = r2[0] + r2[1] + r2[2] + r2[3];
  }
}

__global__ __launch_bounds__(64) void final_kernel(
    const float* __restrict__ blockSums, int nBlocks,
    const float* __restrict__ gaf, const float* __restrict__ baf,
    const float* __restrict__ Wout, float* __restrict__ out, int Q) {
  int tid = threadIdx.x;
  float s1 = 0.0f, s2 = 0.0f;
  for (int b = tid; b < nBlocks; b += 64) {
    s1 += blockSums[b * 2];
    s2 += blockSums[b * 2 + 1];
  }
#pragma unroll
  for (int m = 1; m < 64; m <<= 1) { s1 += __shfl_xor(s1, m); s2 += __shfl_xor(s2, m); }
  if (tid == 0) {
    float e1 = s1 / (float)Q, e2 = s2 / (float)Q;
    float good = gaf[0] * Wout[0] + gaf[1] * Wout[1] + gaf[2] * Wout[2] + gaf[3] * Wout[3] + e1 * Wout[4];
    float bad  = baf[0] * Wout[0] + baf[1] * Wout[1] + baf[2] * Wout[2] + baf[3] * Wout[3] + e2 * Wout[4];
    float loss = fmaxf(0.0f, 1.0f + bad - good);
    out[0] = loss; out[1] = good; out[2] = bad;
  }
}

extern "C" void kernel_launch(void* const* d_in, const int* in_sizes, int n_in,
                              void* d_out, int out_size, void* d_ws, size_t ws_size,
                              hipStream_t stream) {
  const float* d1   = (const float*)d_in[0];
  const float* d2   = (const float*)d_in[1];
  const float* qe   = (const float*)d_in[2];
  const float* qidf = (const float*)d_in[3];
  const float* gaf  = (const float*)d_in[4];
  const float* baf  = (const float*)d_in[5];
  const float* Wc   = (const float*)d_in[6];
  const float* bc   = (const float*)d_in[7];
  const float* Wqw  = (const float*)d_in[8];
  const float* Wq1  = (const float*)d_in[9];
  const float* Wq2  = (const float*)d_in[10];
  const float* Wout = (const float*)d_in[11];
  int D = in_sizes[0] / EMB;
  int Q = in_sizes[2] / EMB;

  unsigned short* us = (unsigned short*)d_ws;
  unsigned short* cmb = us; us += (size_t)D * 128;   // keep qrA directly after cmb:
  unsigned short* qrA = us; us += (size_t)Q * 32;    // absorbs any dead prefetch tail
  unsigned short* qcA = us; us += (size_t)Q * 32;
  float* fp = (float*)us;
  float* logits    = fp; fp += Q;
  float* partials  = fp; fp += (size_t)Q * NS * 20;
  float* blockSums = fp; fp += (Q / 16) * 2;

  int grid = (Q >> 8) + 2 * (D >> 8);
  prep_all_kernel<<<grid, 256, 0, stream>>>(qe, d1, d2, Q, D, Wc, bc, qidf, Wqw,
                                            qrA, qcA, cmb, logits);
  main_kernel<<<(Q / 16) * NS, 256, 0, stream>>>(qrA, qcA, cmb, partials, Q, D);
  pool_kernel<<<Q / 16, 256, 0, stream>>>(logits, partials, Wq1, Wq2, blockSums, Q);
  final_kernel<<<1, 64, 0, stream>>>(blockSums, Q / 16, gaf, baf, Wout, (float*)d_out, Q);
}

// Round 7
// 62.480 us; speedup vs baseline: 1.2265x; 1.2265x over previous
//
#include <hip/hip_runtime.h>
#include <hip/hip_bf16.h>
#include <math.h>

#define EMB 30
#define NS 16   // D splits (one per block); partials layout [q][NS][20]
#define JT 512  // j's per block (D/NS)
#define SUB 128 // j's per LDS subtile (32 KB)

typedef __attribute__((ext_vector_type(8))) short bf16x8;
typedef __attribute__((ext_vector_type(4))) float f32x4;
typedef __attribute__((ext_vector_type(4))) unsigned u32x4;
typedef __attribute__((ext_vector_type(2))) _Float16 f16x2;

__device__ __forceinline__ float leakyf(float x) { return x > 0.0f ? x : 0.1f * x; }

__device__ __forceinline__ unsigned short f2b(float x) {
  __hip_bfloat16 h = __float2bfloat16(x);
  union { __hip_bfloat16 h; unsigned short u; } cv;
  cv.h = h;
  return cv.u;
}

// true packed f16 min/max — forces v_pk_*_f16
__device__ __forceinline__ unsigned pkmax(unsigned a, unsigned b) {
  unsigned d;
  asm("v_pk_max_f16 %0, %1, %2" : "=v"(d) : "v"(a), "v"(b));
  return d;
}
__device__ __forceinline__ unsigned pkmin(unsigned a, unsigned b) {
  unsigned d;
  asm("v_pk_min_f16 %0, %1, %2" : "=v"(d) : "v"(a), "v"(b));
  return d;
}
__device__ __forceinline__ unsigned cvtpku(float a, float b) {
  return __builtin_bit_cast(unsigned, __builtin_amdgcn_cvt_pkrtz(a, b));
}

// packed insert into descending-sorted t[5]
__device__ __forceinline__ void ins5h(unsigned (&t)[5], unsigned v) {
  t[4] = pkmax(t[4], v);
  unsigned a;
  a = pkmax(t[3], t[4]); t[4] = pkmin(t[3], t[4]); t[3] = a;
  a = pkmax(t[2], t[3]); t[3] = pkmin(t[2], t[3]); t[2] = a;
  a = pkmax(t[1], t[2]); t[2] = pkmin(t[1], t[2]); t[1] = a;
  a = pkmax(t[0], t[1]); t[1] = pkmin(t[0], t[1]); t[0] = a;
}

// packed top-5 of merge(a,b), both sorted descending
__device__ __forceinline__ void merge5h(unsigned (&a)[5], const unsigned (&b)[5]) {
  unsigned c0 = pkmax(a[0], b[0]);
  unsigned c1 = pkmax(pkmax(pkmin(a[0], b[0]), a[1]), b[1]);
  unsigned c2 = pkmax(pkmax(pkmin(a[0], b[1]), pkmin(a[1], b[0])), pkmax(a[2], b[2]));
  unsigned c3 = pkmax(pkmax(pkmin(a[0], b[2]), pkmin(a[1], b[1])),
                      pkmax(pkmin(a[2], b[0]), pkmax(a[3], b[3])));
  unsigned c4 = pkmax(pkmax(pkmax(pkmin(a[0], b[3]), pkmin(a[1], b[2])),
                            pkmax(pkmin(a[2], b[1]), pkmin(a[3], b[0]))),
                      pkmax(a[4], b[4]));
  a[0] = c0; a[1] = c1; a[2] = c2; a[3] = c3; a[4] = c4;
}

// float top-5 merge (pool stage)
__device__ __forceinline__ void merge5(float (&a)[5], const float (&b)[5]) {
  float c0 = fmaxf(a[0], b[0]);
  float c1 = fmaxf(fmaxf(fminf(a[0], b[0]), a[1]), b[1]);
  float c2 = fmaxf(fmaxf(fminf(a[0], b[1]), fminf(a[1], b[0])), fmaxf(a[2], b[2]));
  float c3 = fmaxf(fmaxf(fminf(a[0], b[2]), fminf(a[1], b[1])),
                   fmaxf(fminf(a[2], b[0]), fmaxf(a[3], b[3])));
  float c4 = fmaxf(fmaxf(fmaxf(fminf(a[0], b[3]), fminf(a[1], b[2])),
                         fmaxf(fminf(a[2], b[1]), fminf(a[3], b[0]))),
                   fmaxf(a[4], b[4]));
  a[0] = c0; a[1] = c1; a[2] = c2; a[3] = c3; a[4] = c4;
}

// butterfly merge round over j-lanes via single-instruction ds_swizzle
template <int PAT>
__device__ __forceinline__ void bfly_round(unsigned (&t)[8][5]) {
#pragma unroll
  for (int li = 0; li < 8; ++li) {
    unsigned b[5];
#pragma unroll
    for (int k = 0; k < 5; ++k)
      b[k] = (unsigned)__builtin_amdgcn_ds_swizzle((int)t[li][k], PAT);
    merge5h(t[li], b);
  }
}

// Fused prep: questions -> qr/qc [L][32] bf16 + logits; docs -> interleaved
// cmb[j] = 256B row (slots: d1r,d1c,d2r,d2c × 32B), dwords XOR-swizzled by
// (j&7)<<2 so the LDS image in main_kernel is bank-conflict-free.
__global__ __launch_bounds__(256) void prep_all_kernel(
    const float* __restrict__ Xq, const float* __restrict__ X1,
    const float* __restrict__ X2, int Q, int D,
    const float* __restrict__ Wc, const float* __restrict__ bc,
    const float* __restrict__ qidf, const float* __restrict__ Wqw,
    unsigned short* __restrict__ qr, unsigned short* __restrict__ qc,
    unsigned short* __restrict__ cmb, float* __restrict__ logits) {
  __shared__ float sX[258 * EMB];
  int tid = threadIdx.x;
  int nbQ = Q >> 8, nbD = D >> 8;
  int b = blockIdx.x;
  const float* X;
  int L, l0, slot = 0;
  bool isQ = false;
  if (b < nbQ) { X = Xq; L = Q; l0 = b << 8; isQ = true; }
  else if (b < nbQ + nbD) { X = X1; L = D; l0 = (b - nbQ) << 8; slot = 0; }
  else { X = X2; L = D; l0 = (b - nbQ - nbD) << 8; slot = 2; }

  int base = l0 * EMB - EMB;
  int lim = L * EMB;
  for (int idx = tid; idx < 258 * EMB; idx += 256) {
    int g = base + idx;
    sX[idx] = (g >= 0 && g < lim) ? X[g] : 0.0f;
  }
  __syncthreads();

  int l = l0 + tid;                    // L is a multiple of 256
  float xm[EMB], x0[EMB], xp[EMB], y[EMB];
#pragma unroll
  for (int i = 0; i < EMB; ++i) xm[i] = sX[tid * EMB + i];
#pragma unroll
  for (int i = 0; i < EMB; ++i) x0[i] = sX[(tid + 1) * EMB + i];
#pragma unroll
  for (int i = 0; i < EMB; ++i) xp[i] = sX[(tid + 2) * EMB + i];

  float sr = 0.0f, sc = 0.0f, lg = 0.0f;
#pragma unroll
  for (int i = 0; i < EMB; ++i) sr += x0[i] * x0[i];
#pragma unroll 1
  for (int o = 0; o < EMB; ++o) {
    float acc = bc[o];                 // uniform -> scalar loads
#pragma unroll
    for (int i = 0; i < EMB; ++i) {
      acc += Wc[o * 90 + i * 3 + 0] * xm[i];
      acc += Wc[o * 90 + i * 3 + 1] * x0[i];
      acc += Wc[o * 90 + i * 3 + 2] * xp[i];
    }
    float v = leakyf(acc) + x0[o];
    y[o] = v;
    sc += v * v;
    lg += v * Wqw[o];
  }
  float rnr = 1.0f / sqrtf(sr);
  float rnc = 1.0f / sqrtf(sc);
  if (isQ) logits[l] = lg + qidf[l] * Wqw[EMB];

  unsigned int rp[16], cp[16];
#pragma unroll
  for (int k = 0; k < 15; ++k) {
    rp[k] = (unsigned int)f2b(x0[2 * k] * rnr) | ((unsigned int)f2b(x0[2 * k + 1] * rnr) << 16);
    cp[k] = (unsigned int)f2b(y[2 * k] * rnc) | ((unsigned int)f2b(y[2 * k + 1] * rnc) << 16);
  }
  rp[15] = 0u; cp[15] = 0u;
  if (isQ) {
    unsigned int* rw = (unsigned int*)(qr + (size_t)l * 32);
    unsigned int* cw = (unsigned int*)(qc + (size_t)l * 32);
#pragma unroll
    for (int k = 0; k < 16; ++k) { rw[k] = rp[k]; cw[k] = cp[k]; }
  } else {
    unsigned int* rowp = (unsigned int*)(cmb + (size_t)l * 128);
    int sx = (l & 7) << 2;
#pragma unroll
    for (int k = 0; k < 16; ++k) {
      rowp[(slot * 16 + k) ^ sx]       = rp[k];
      rowp[((slot + 1) * 16 + k) ^ sx] = cp[k];
    }
  }
}

// Block = 4 waves = 4 q-tiles (64 q-rows) × 1 D-split (JT j's).
// Doc rows staged to double-buffered LDS (reg-staged, XOR-swizzled layout);
// all 4 waves share each staged subtile. Per-wave: MFMA sims + packed-f16
// top-5 + 4-round ds_swizzle butterfly; writers store partials directly.
__global__ __launch_bounds__(256) void main_kernel(
    const unsigned short* __restrict__ qrA, const unsigned short* __restrict__ qcA,
    const unsigned* __restrict__ cmb32,
    float* __restrict__ partials, int Q, int D) {
  __shared__ __align__(16) unsigned lds[2][SUB * 64];   // 2 x 32 KB
  int tid = threadIdx.x;
  int wave = tid >> 6, lane = tid & 63;
  int lo = lane & 15, hi = lane >> 4;
  int qt = blockIdx.x >> 4, ds = blockIdx.x & (NS - 1);
  int qrow = qt * 64 + wave * 16 + lo;
  bf16x8 aR = *(const bf16x8*)(qrA + (size_t)qrow * 32 + hi * 8);
  bf16x8 aC = *(const bf16x8*)(qcA + (size_t)qrow * 32 + hi * 8);

  unsigned t[8][5];                    // lists: [r*2+0]=raw(d1,d2) [r*2+1]=conv
#pragma unroll
  for (int li = 0; li < 8; ++li)
#pragma unroll
    for (int k = 0; k < 5; ++k) t[li][k] = 0xC000C000u;  // packed f16 -2.0

  const u32x4* gsrc = (const u32x4*)(cmb32 + (size_t)ds * JT * 64);
  u32x4 R[8];
  // stage subtile 0
#pragma unroll
  for (int i = 0; i < 8; ++i) R[i] = gsrc[i * 256 + tid];
#pragma unroll
  for (int i = 0; i < 8; ++i) ((u32x4*)lds[0])[i * 256 + tid] = R[i];

  int swzA = ((lo & 7) << 2);
  int c0 = (0  + hi * 4) ^ swzA;
  int c1 = (16 + hi * 4) ^ swzA;
  int c2 = (32 + hi * 4) ^ swzA;
  int c3 = (48 + hi * 4) ^ swzA;

#pragma unroll 1
  for (int st = 0; st < 4; ++st) {
    __syncthreads();                   // lds[st&1] ready for all waves
    if (st < 3) {                      // issue next subtile's loads early (T14)
#pragma unroll
      for (int i = 0; i < 8; ++i) R[i] = gsrc[(st + 1) * 2048 + i * 256 + tid];
    }
    const unsigned* L = lds[st & 1];
#pragma unroll
    for (int it = 0; it < 8; ++it) {
      const unsigned* rp = L + (it * 16 + lo) * 64;
      bf16x8 X0 = *(const bf16x8*)(rp + c0);
      bf16x8 X1 = *(const bf16x8*)(rp + c1);
      bf16x8 X2 = *(const bf16x8*)(rp + c2);
      bf16x8 X3 = *(const bf16x8*)(rp + c3);
      f32x4 z = {0.0f, 0.0f, 0.0f, 0.0f};
      f32x4 s0 = __builtin_amdgcn_mfma_f32_16x16x32_bf16(aR, X0, z, 0, 0, 0);
      f32x4 s1 = __builtin_amdgcn_mfma_f32_16x16x32_bf16(aC, X1, z, 0, 0, 0);
      f32x4 s2 = __builtin_amdgcn_mfma_f32_16x16x32_bf16(aR, X2, z, 0, 0, 0);
      f32x4 s3 = __builtin_amdgcn_mfma_f32_16x16x32_bf16(aC, X3, z, 0, 0, 0);
#pragma unroll
      for (int r = 0; r < 4; ++r) {
        ins5h(t[r * 2 + 0], cvtpku(s0[r], s2[r]));   // raw: lo=d1, hi=d2
        ins5h(t[r * 2 + 1], cvtpku(s1[r], s3[r]));   // conv
      }
    }
    __syncthreads();                   // all waves done reading lds[st&1]
    if (st < 3) {
#pragma unroll
      for (int i = 0; i < 8; ++i) ((u32x4*)lds[(st + 1) & 1])[i * 256 + tid] = R[i];
    }
  }

  // butterfly over the 16 j-lanes (xor 1,2,4,8), single-instr ds_swizzle
  bfly_round<0x041F>(t);
  bfly_round<0x081F>(t);
  bfly_round<0x101F>(t);
  bfly_round<0x201F>(t);

  if (lo == 0) {
#pragma unroll
    for (int r = 0; r < 4; ++r) {
      int q = qt * 64 + wave * 16 + hi * 4 + r;
      float* dst = partials + ((size_t)q * NS + ds) * 20;
#pragma unroll
      for (int k = 0; k < 5; ++k) {
        f16x2 t0 = __builtin_bit_cast(f16x2, t[r * 2 + 0][k]);
        f16x2 t1 = __builtin_bit_cast(f16x2, t[r * 2 + 1][k]);
        dst[k]      = (float)t0[0];    // d1 raw
        dst[5 + k]  = (float)t1[0];    // d1 conv
        dst[10 + k] = (float)t0[1];    // d2 raw
        dst[15 + k] = (float)t1[1];    // d2 conv
      }
    }
  }
}

// Parallel pool: block = 16 q's x 16 splits. Redundant block softmax (M,S),
// LDS-staged coalesced partial loads, shfl-tree split merge, MLP, block sums.
__global__ __launch_bounds__(256) void pool_kernel(
    const float* __restrict__ logits, const float* __restrict__ partials,
    const float* __restrict__ W1, const float* __restrict__ W2,
    float* __restrict__ blockSums, int Q) {
  __shared__ float sred[4];
  __shared__ float sP[16 * 321];
  int tid = threadIdx.x;
  int lane = tid & 63, wave = tid >> 6;

  float lmax = -3.0e38f;
  for (int q = tid; q < Q; q += 256) lmax = fmaxf(lmax, logits[q]);
#pragma unroll
  for (int m = 1; m < 64; m <<= 1) lmax = fmaxf(lmax, __shfl_xor(lmax, m));
  if (lane == 0) sred[wave] = lmax;
  __syncthreads();
  float M = fmaxf(fmaxf(sred[0], sred[1]), fmaxf(sred[2], sred[3]));
  __syncthreads();
  float lsum = 0.0f;
  for (int q = tid; q < Q; q += 256) lsum += expf(logits[q] - M);
#pragma unroll
  for (int m = 1; m < 64; m <<= 1) lsum += __shfl_xor(lsum, m);
  if (lane == 0) sred[wave] = lsum;
  __syncthreads();
  float rS = 1.0f / (sred[0] + sred[1] + sred[2] + sred[3]);

  size_t base = (size_t)blockIdx.x * 16 * NS * 20;
  for (int k = tid; k < 16 * NS * 20; k += 256) {
    int ql = k / 320, r = k - ql * 320;
    sP[ql * 321 + r] = partials[base + k];
  }
  __syncthreads();

  int ql = tid >> 4, dsp = tid & 15;
  int qglob = blockIdx.x * 16 + ql;
  float T[4][5];
#pragma unroll
  for (int li = 0; li < 4; ++li)
#pragma unroll
    for (int k = 0; k < 5; ++k) T[li][k] = sP[ql * 321 + dsp * 20 + li * 5 + k];
#pragma unroll
  for (int m = 8; m >= 1; m >>= 1) {
#pragma unroll
    for (int li = 0; li < 4; ++li) {
      float b[5];
#pragma unroll
      for (int k = 0; k < 5; ++k) b[k] = __shfl_xor(T[li][k], m);
      merge5(T[li], b);
    }
  }
  float s1 = 0.0f, s2 = 0.0f;
  if (dsp == 0) {
    float w = expf(logits[qglob] - M) * rS;
#pragma unroll
    for (int d = 0; d < 2; ++d) {
      const float (&Ti)[5] = T[d ? 2 : 0];   // raw
      const float (&Ts)[5] = T[d ? 3 : 1];   // conv
      float c = 0.0f;
#pragma unroll
      for (int k = 0; k < 5; ++k) c += (Ti[k] > 0.999f) ? 1.0f : 0.0f;  // min(cnt,5)
      float tmp[6];
      tmp[0] = (Ti[0] > 0.999f) ? 1.0f : 0.0f;
      tmp[1] = c * 0.2f;
      tmp[2] = Ti[0];
      tmp[3] = (Ti[0] + Ti[1] + Ti[2] + Ti[3] + Ti[4]) * 0.2f;
      tmp[4] = Ts[0];
      tmp[5] = (Ts[0] + Ts[1] + Ts[2] + Ts[3] + Ts[4]) * 0.2f;
      float lov = 0.0f;
#pragma unroll
      for (int r = 0; r < 8; ++r) {
        float h = 0.0f;
#pragma unroll
        for (int cidx = 0; cidx < 6; ++cidx) h += W1[r * 6 + cidx] * tmp[cidx];
        lov += W2[r] * leakyf(h);
      }
      if (d == 0) s1 = lov * w; else s2 = lov * w;
    }
  }
  __shared__ float r1[4], r2[4];
#pragma unroll
  for (int m = 1; m < 64; m <<= 1) { s1 += __shfl_xor(s1, m); s2 += __shfl_xor(s2, m); }
  if (lane == 0) { r1[wave] = s1; r2[wave] = s2; }
  __syncthreads();
  if (tid == 0) {
    blockSums[blockIdx.x * 2]     = r1[0] + r1[1] + r1[2] + r1[3];
    blockSums[blockIdx.x * 2 + 1] = r2[0] + r2[1] + r2[2] + r2[3];
  }
}

__global__ __launch_bounds__(64) void final_kernel(
    const float* __restrict__ blockSums, int nBlocks,
    const float* __restrict__ gaf, const float* __restrict__ baf,
    const float* __restrict__ Wout, float* __restrict__ out, int Q) {
  int tid = threadIdx.x;
  float s1 = 0.0f, s2 = 0.0f;
  for (int b = tid; b < nBlocks; b += 64) {
    s1 += blockSums[b * 2];
    s2 += blockSums[b * 2 + 1];
  }
#pragma unroll
  for (int m = 1; m < 64; m <<= 1) { s1 += __shfl_xor(s1, m); s2 += __shfl_xor(s2, m); }
  if (tid == 0) {
    float e1 = s1 / (float)Q, e2 = s2 / (float)Q;
    float good = gaf[0] * Wout[0] + gaf[1] * Wout[1] + gaf[2] * Wout[2] + gaf[3] * Wout[3] + e1 * Wout[4];
    float bad  = baf[0] * Wout[0] + baf[1] * Wout[1] + baf[2] * Wout[2] + baf[3] * Wout[3] + e2 * Wout[4];
    float loss = fmaxf(0.0f, 1.0f + bad - good);
    out[0] = loss; out[1] = good; out[2] = bad;
  }
}

extern "C" void kernel_launch(void* const* d_in, const int* in_sizes, int n_in,
                              void* d_out, int out_size, void* d_ws, size_t ws_size,
                              hipStream_t stream) {
  const float* d1   = (const float*)d_in[0];
  const float* d2   = (const float*)d_in[1];
  const float* qe   = (const float*)d_in[2];
  const float* qidf = (const float*)d_in[3];
  const float* gaf  = (const float*)d_in[4];
  const float* baf  = (const float*)d_in[5];
  const float* Wc   = (const float*)d_in[6];
  const float* bc   = (const float*)d_in[7];
  const float* Wqw  = (const float*)d_in[8];
  const float* Wq1  = (const float*)d_in[9];
  const float* Wq2  = (const float*)d_in[10];
  const float* Wout = (const float*)d_in[11];
  int D = in_sizes[0] / EMB;
  int Q = in_sizes[2] / EMB;

  unsigned short* us = (unsigned short*)d_ws;
  unsigned short* cmb = us; us += (size_t)D * 128;
  unsigned short* qrA = us; us += (size_t)Q * 32;
  unsigned short* qcA = us; us += (size_t)Q * 32;
  float* fp = (float*)us;
  float* logits    = fp; fp += Q;
  float* partials  = fp; fp += (size_t)Q * NS * 20;
  float* blockSums = fp; fp += (Q / 16) * 2;

  int grid = (Q >> 8) + 2 * (D >> 8);
  prep_all_kernel<<<grid, 256, 0, stream>>>(qe, d1, d2, Q, D, Wc, bc, qidf, Wqw,
                                            qrA, qcA, cmb, logits);
  main_kernel<<<(Q / 64) * NS, 256, 0, stream>>>(qrA, qcA, (const unsigned*)cmb,
                                                 partials, Q, D);
  pool_kernel<<<Q / 16, 256, 0, stream>>>(logits, partials, Wq1, Wq2, blockSums, Q);
  final_kernel<<<1, 64, 0, stream>>>(blockSums, Q / 16, gaf, baf, Wout, (float*)d_out, Q);
}